// Round 5
// baseline (284.102 us; speedup 1.0000x reference)
//
#include <hip/hip_runtime.h>
#include <hip/hip_bf16.h>

namespace {

constexpr int S = 2048;
constexpr int D = 64;
constexpr int BH = 24;        // 2 batches * 12 heads
constexpr int QT = 64;        // q rows per block
constexpr int KT = 64;        // keys per tile
constexpr int NKT = S / KT;   // 32
constexpr int PAD = 72;       // LDS row stride in ushorts (16B-aligned rows; R2 lesson)

typedef __attribute__((ext_vector_type(8))) __bf16 bf16x8;
typedef __attribute__((ext_vector_type(4))) __bf16 bf16x4;
typedef __attribute__((ext_vector_type(4))) float  f32x4;
typedef __attribute__((ext_vector_type(4))) unsigned short u16x4;

// f32x4 -> bf16x4 via native v_cvt_pk_bf16_f32 (RNE)
__device__ inline bf16x4 cvt4(f32x4 f) {
    return __builtin_convertvector(f, bf16x4);
}

// ---------------- prologue kernels (write bf16 staging into d_ws) ----------------

__global__ __launch_bounds__(256)
void cast_bf16_kernel(const float* __restrict__ src, unsigned short* __restrict__ dst, int n4) {
    int i = blockIdx.x * 256 + threadIdx.x;
    const int stride = gridDim.x * 256;
    for (; i < n4; i += stride) {
        f32x4 f = *reinterpret_cast<const f32x4*>(src + 4 * (size_t)i);
        *reinterpret_cast<bf16x4*>(dst + 4 * (size_t)i) = cvt4(f);
    }
}

// V [bh][s][d] f32 -> Vt [bh][d][s] bf16 (64x64 LDS tile transpose)
__global__ __launch_bounds__(256)
void transpose_v_kernel(const float* __restrict__ v, unsigned short* __restrict__ vt) {
    __shared__ unsigned short Ls[64][PAD];
    const int bh = blockIdx.y;
    const int s0 = blockIdx.x * 64;
    const int tid = threadIdx.x;
    #pragma unroll
    for (int ii = 0; ii < 4; ++ii) {
        int idx = tid + ii * 256;
        int sr = idx >> 4, dc = (idx & 15) * 4;
        f32x4 f = *reinterpret_cast<const f32x4*>(v + ((size_t)bh * S + s0 + sr) * D + dc);
        *reinterpret_cast<bf16x4*>(&Ls[sr][dc]) = cvt4(f);
    }
    __syncthreads();
    #pragma unroll
    for (int ii = 0; ii < 4; ++ii) {
        int idx = tid + ii * 256;
        int dr = idx >> 4, sc = (idx & 15) * 4;
        u16x4 w = { Ls[sc + 0][dr], Ls[sc + 1][dr], Ls[sc + 2][dr], Ls[sc + 3][dr] };
        *reinterpret_cast<u16x4*>(vt + ((size_t)bh * D + dr) * S + s0 + sc) = w;
    }
}

// ---------------- main kernel: barrier-free, direct-fragment loads ----------------

__global__ __launch_bounds__(256, 3)
void sdpa_main(const unsigned short* __restrict__ Qb,
               const unsigned short* __restrict__ Kb,
               const unsigned short* __restrict__ Vtb,
               float* __restrict__ out, float* __restrict__ attn) {
    __shared__ unsigned short QPs[QT][PAD];   // P round-trip only; rows wave-private

    const int tid  = threadIdx.x;
    const int wid  = tid >> 6;
    const int lane = tid & 63;
    const int g    = lane >> 4;
    const int r16  = lane & 15;

    // XCD-aware swizzle: 768 blocks, 96 contiguous logical ids per XCD (768%8==0)
    const int logical = (blockIdx.x & 7) * 96 + (blockIdx.x >> 3);
    const int bh = logical >> 5;
    const int q0 = (logical & 31) * QT;
    const int qrow = q0 + wid * 16 + r16;

    const unsigned short* Kw = Kb  + (size_t)bh * S * D + (size_t)r16 * D + g * 8;
    const unsigned short* Vw = Vtb + (size_t)bh * D * S + (size_t)r16 * S + g * 8;
    const unsigned short* Qw = Qb  + ((size_t)bh * S + qrow) * D + g * 8;
    float* attnw = attn + ((size_t)bh * S + qrow) * S;
    float* outg  = out  + ((size_t)bh * S + q0) * D;

    // Q B-fragments direct from global (contiguous 2KB per wave)
    const bf16x8 bQ0 = *reinterpret_cast<const bf16x8*>(Qw);
    const bf16x8 bQ1 = *reinterpret_cast<const bf16x8*>(Qw + 32);

    auto loadK = [&](bf16x8* dst, int t) {
        const unsigned short* p = Kw + (size_t)t * KT * D;
        #pragma unroll
        for (int cf = 0; cf < 4; ++cf) {
            dst[2 * cf]     = *reinterpret_cast<const bf16x8*>(p + cf * 16 * D);
            dst[2 * cf + 1] = *reinterpret_cast<const bf16x8*>(p + cf * 16 * D + 32);
        }
    };

    // ================= phase 1: row sums of exp(scores/64), no LDS =================
    float rs = 0.f;
    {
        bf16x8 ka[8], kb2[8];
        auto qkexp = [&](const bf16x8* src) {
            #pragma unroll
            for (int cf = 0; cf < 4; ++cf) {
                f32x4 acc = {0.f, 0.f, 0.f, 0.f};
                acc = __builtin_amdgcn_mfma_f32_16x16x32_bf16(src[2 * cf],     bQ0, acc, 0, 0, 0);
                acc = __builtin_amdgcn_mfma_f32_16x16x32_bf16(src[2 * cf + 1], bQ1, acc, 0, 0, 0);
                #pragma unroll
                for (int e = 0; e < 4; ++e)
                    rs += __expf(acc[e] * (1.0f / 64.0f));
            }
        };
        loadK(ka, 0);
        for (int tt = 0; tt < 16; ++tt) {
            loadK(kb2, 2 * tt + 1);
            qkexp(ka);
            if (tt < 15) loadK(ka, 2 * tt + 2);
            qkexp(kb2);
        }
    }
    rs += __shfl_xor(rs, 16, 64);
    rs += __shfl_xor(rs, 32, 64);
    const float inv = 1.0f / rs;

    // ===== phase 2: recompute, write attn (nt float4), accumulate PV — no barriers =====
    f32x4 oacc[4];
    #pragma unroll
    for (int n = 0; n < 4; ++n) oacc[n] = {0.f, 0.f, 0.f, 0.f};

    unsigned short* prow = &QPs[wid * 16 + r16][0];

    auto tile2 = [&](const bf16x8* src, int t) {
        // V fragments issued first; consumed ~200cy later at PV
        bf16x8 vv[8];
        #pragma unroll
        for (int n = 0; n < 4; ++n) {
            const unsigned short* p = Vw + (size_t)n * 16 * S + (size_t)t * KT;
            vv[2 * n]     = *reinterpret_cast<const bf16x8*>(p);
            vv[2 * n + 1] = *reinterpret_cast<const bf16x8*>(p + 32);
        }
        #pragma unroll
        for (int cf = 0; cf < 4; ++cf) {
            f32x4 acc = {0.f, 0.f, 0.f, 0.f};
            acc = __builtin_amdgcn_mfma_f32_16x16x32_bf16(src[2 * cf],     bQ0, acc, 0, 0, 0);
            acc = __builtin_amdgcn_mfma_f32_16x16x32_bf16(src[2 * cf + 1], bQ1, acc, 0, 0, 0);
            f32x4 pst;
            #pragma unroll
            for (int e = 0; e < 4; ++e)
                pst[e] = __expf(acc[e] * (1.0f / 64.0f)) * inv;
            __builtin_nontemporal_store(pst, reinterpret_cast<f32x4*>(
                attnw + (size_t)t * KT + cf * 16 + g * 4));
            *reinterpret_cast<bf16x4*>(prow + cf * 16 + g * 4) = cvt4(pst);
        }
        // P round-trip (wave-private LDS rows; compiler inserts lgkmcnt, no barrier)
        bf16x8 aP0 = *reinterpret_cast<const bf16x8*>(prow + g * 8);
        bf16x8 aP1 = *reinterpret_cast<const bf16x8*>(prow + 32 + g * 8);
        #pragma unroll
        for (int n = 0; n < 4; ++n) {
            oacc[n] = __builtin_amdgcn_mfma_f32_16x16x32_bf16(aP0, vv[2 * n],     oacc[n], 0, 0, 0);
            oacc[n] = __builtin_amdgcn_mfma_f32_16x16x32_bf16(aP1, vv[2 * n + 1], oacc[n], 0, 0, 0);
        }
    };

    {
        bf16x8 ka[8], kb2[8];
        loadK(ka, 0);
        for (int tt = 0; tt < 16; ++tt) {
            loadK(kb2, 2 * tt + 1);
            tile2(ka, 2 * tt);
            if (tt < 15) loadK(ka, 2 * tt + 2);
            tile2(kb2, 2 * tt + 1);
        }
    }

    // ---- epilogue: out tile; C[q][d]: q = wid*16 + g*4 + e, d = n*16 + r16 ----
    #pragma unroll
    for (int n = 0; n < 4; ++n) {
        #pragma unroll
        for (int e = 0; e < 4; ++e) {
            __builtin_nontemporal_store(oacc[n][e],
                outg + (size_t)(wid * 16 + g * 4 + e) * D + n * 16 + r16);
        }
    }
}

// ---------------- fallback (proven R4 kernel) if ws too small ----------------

__global__ __launch_bounds__(256, 3)
void sdpa_fallback(const float* __restrict__ q,
                   const float* __restrict__ k,
                   const float* __restrict__ v,
                   float* __restrict__ out,
                   float* __restrict__ attn) {
    __shared__ unsigned short Ks[2][KT][PAD];
    __shared__ unsigned short Vt[2][D][PAD];
    __shared__ unsigned short QPs[QT][PAD];

    const int tid  = threadIdx.x;
    const int wid  = tid >> 6;
    const int lane = tid & 63;
    const int g    = lane >> 4;
    const int r16  = lane & 15;
    const int bh   = blockIdx.y;
    const int q0   = blockIdx.x * QT;

    const float* qg = q + ((size_t)bh * S + q0) * D;
    const float* kg = k + (size_t)bh * S * D;
    const float* vg = v + (size_t)bh * S * D;
    float* attng = attn + ((size_t)bh * S + q0) * S;
    float* outg  = out  + ((size_t)bh * S + q0) * D;

    #pragma unroll
    for (int ii = 0; ii < 4; ++ii) {
        int idx = tid + ii * 256;
        int r = idx >> 4, c = (idx & 15) * 4;
        f32x4 f = *reinterpret_cast<const f32x4*>(qg + r * D + c);
        *reinterpret_cast<bf16x4*>(&QPs[r][c]) = cvt4(f);
    }
    __syncthreads();
    const bf16x8 bQ0 = *(const bf16x8*)&QPs[wid * 16 + r16][g * 8];
    const bf16x8 bQ1 = *(const bf16x8*)&QPs[wid * 16 + r16][32 + g * 8];

    float rs = 0.0f;
    f32x4 pK[4];

    #pragma unroll
    for (int ii = 0; ii < 4; ++ii) {
        int idx = tid + ii * 256;
        int r = idx >> 4, c = (idx & 15) * 4;
        pK[ii] = *reinterpret_cast<const f32x4*>(kg + r * D + c);
    }
    #pragma unroll
    for (int ii = 0; ii < 4; ++ii) {
        int idx = tid + ii * 256;
        int r = idx >> 4, c = (idx & 15) * 4;
        *reinterpret_cast<bf16x4*>(&Ks[0][r][c]) = cvt4(pK[ii]);
    }
    __syncthreads();

    for (int t = 0; t < NKT; ++t) {
        const int cur = t & 1;
        if (t + 1 < NKT) {
            const float* ktg = kg + (size_t)(t + 1) * KT * D;
            #pragma unroll
            for (int ii = 0; ii < 4; ++ii) {
                int idx = tid + ii * 256;
                int r = idx >> 4, c = (idx & 15) * 4;
                pK[ii] = *reinterpret_cast<const f32x4*>(ktg + r * D + c);
            }
        }
        #pragma unroll
        for (int cf = 0; cf < 4; ++cf) {
            bf16x8 aK0 = *(const bf16x8*)&Ks[cur][cf * 16 + r16][g * 8];
            bf16x8 aK1 = *(const bf16x8*)&Ks[cur][cf * 16 + r16][32 + g * 8];
            f32x4 acc = {0.f, 0.f, 0.f, 0.f};
            acc = __builtin_amdgcn_mfma_f32_16x16x32_bf16(aK0, bQ0, acc, 0, 0, 0);
            acc = __builtin_amdgcn_mfma_f32_16x16x32_bf16(aK1, bQ1, acc, 0, 0, 0);
            #pragma unroll
            for (int e = 0; e < 4; ++e)
                rs += __expf(acc[e] * (1.0f / 64.0f));
        }
        if (t + 1 < NKT) {
            const int nxt = (t + 1) & 1;
            #pragma unroll
            for (int ii = 0; ii < 4; ++ii) {
                int idx = tid + ii * 256;
                int r = idx >> 4, c = (idx & 15) * 4;
                *reinterpret_cast<bf16x4*>(&Ks[nxt][r][c]) = cvt4(pK[ii]);
            }
            __syncthreads();
        }
    }
    rs += __shfl_xor(rs, 16, 64);
    rs += __shfl_xor(rs, 32, 64);
    const float inv = 1.0f / rs;

    f32x4 oacc[4];
    #pragma unroll
    for (int n = 0; n < 4; ++n) oacc[n] = {0.f, 0.f, 0.f, 0.f};

    f32x4 pV[4];
    const int vk0 = (tid & 15) * 4;
    const int vc  = (tid >> 4) * 4;

    #pragma unroll
    for (int ii = 0; ii < 4; ++ii) {
        int idx = tid + ii * 256;
        int r = idx >> 4, c = (idx & 15) * 4;
        pK[ii] = *reinterpret_cast<const f32x4*>(kg + r * D + c);
        pV[ii] = *reinterpret_cast<const f32x4*>(vg + (vk0 + ii) * D + vc);
    }
    #pragma unroll
    for (int ii = 0; ii < 4; ++ii) {
        int idx = tid + ii * 256;
        int r = idx >> 4, c = (idx & 15) * 4;
        *reinterpret_cast<bf16x4*>(&Ks[0][r][c]) = cvt4(pK[ii]);
    }
    #pragma unroll
    for (int j = 0; j < 4; ++j) {
        f32x4 col = { pV[0][j], pV[1][j], pV[2][j], pV[3][j] };
        *reinterpret_cast<bf16x4*>(&Vt[0][vc + j][vk0]) = cvt4(col);
    }
    __syncthreads();

    for (int t = 0; t < NKT; ++t) {
        const int cur = t & 1;
        if (t + 1 < NKT) {
            const float* ktg = kg + (size_t)(t + 1) * KT * D;
            const float* vtg = vg + (size_t)(t + 1) * KT * D;
            #pragma unroll
            for (int ii = 0; ii < 4; ++ii) {
                int idx = tid + ii * 256;
                int r = idx >> 4, c = (idx & 15) * 4;
                pK[ii] = *reinterpret_cast<const f32x4*>(ktg + r * D + c);
                pV[ii] = *reinterpret_cast<const f32x4*>(vtg + (vk0 + ii) * D + vc);
            }
        }
        #pragma unroll
        for (int cf = 0; cf < 4; ++cf) {
            bf16x8 aK0 = *(const bf16x8*)&Ks[cur][cf * 16 + r16][g * 8];
            bf16x8 aK1 = *(const bf16x8*)&Ks[cur][cf * 16 + r16][32 + g * 8];
            f32x4 acc = {0.f, 0.f, 0.f, 0.f};
            acc = __builtin_amdgcn_mfma_f32_16x16x32_bf16(aK0, bQ0, acc, 0, 0, 0);
            acc = __builtin_amdgcn_mfma_f32_16x16x32_bf16(aK1, bQ1, acc, 0, 0, 0);
            f32x4 pst;
            #pragma unroll
            for (int e = 0; e < 4; ++e)
                pst[e] = __expf(acc[e] * (1.0f / 64.0f)) * inv;
            __builtin_nontemporal_store(pst, reinterpret_cast<f32x4*>(
                attng + (size_t)(wid * 16 + r16) * S + t * KT + cf * 16 + g * 4));
            *reinterpret_cast<bf16x4*>(&QPs[wid * 16 + r16][cf * 16 + g * 4]) = cvt4(pst);
        }
        bf16x8 aP0 = *(const bf16x8*)&QPs[wid * 16 + r16][g * 8];
        bf16x8 aP1 = *(const bf16x8*)&QPs[wid * 16 + r16][32 + g * 8];
        #pragma unroll
        for (int n = 0; n < 4; ++n) {
            bf16x8 bv0 = *(const bf16x8*)&Vt[cur][n * 16 + r16][g * 8];
            bf16x8 bv1 = *(const bf16x8*)&Vt[cur][n * 16 + r16][32 + g * 8];
            oacc[n] = __builtin_amdgcn_mfma_f32_16x16x32_bf16(aP0, bv0, oacc[n], 0, 0, 0);
            oacc[n] = __builtin_amdgcn_mfma_f32_16x16x32_bf16(aP1, bv1, oacc[n], 0, 0, 0);
        }
        if (t + 1 < NKT) {
            const int nxt = (t + 1) & 1;
            #pragma unroll
            for (int ii = 0; ii < 4; ++ii) {
                int idx = tid + ii * 256;
                int r = idx >> 4, c = (idx & 15) * 4;
                *reinterpret_cast<bf16x4*>(&Ks[nxt][r][c]) = cvt4(pK[ii]);
            }
            #pragma unroll
            for (int j = 0; j < 4; ++j) {
                f32x4 col = { pV[0][j], pV[1][j], pV[2][j], pV[3][j] };
                *reinterpret_cast<bf16x4*>(&Vt[nxt][vc + j][vk0]) = cvt4(col);
            }
            __syncthreads();
        }
    }

    #pragma unroll
    for (int n = 0; n < 4; ++n) {
        #pragma unroll
        for (int e = 0; e < 4; ++e) {
            __builtin_nontemporal_store(oacc[n][e],
                outg + (size_t)(wid * 16 + g * 4 + e) * D + n * 16 + r16);
        }
    }
}

} // namespace

extern "C" void kernel_launch(void* const* d_in, const int* in_sizes, int n_in,
                              void* d_out, int out_size, void* d_ws, size_t ws_size,
                              hipStream_t stream) {
    const float* q = (const float*)d_in[0];
    const float* k = (const float*)d_in[1];
    const float* v = (const float*)d_in[2];
    float* out  = (float*)d_out;
    float* attn = out + (size_t)BH * S * D;   // outputs concatenated: (out, attn)

    constexpr size_t NEL  = (size_t)BH * S * D;   // 3,145,728 elements per tensor
    constexpr size_t NEED = NEL * 2 * 3;          // Qb + Kb + Vtb in bf16

    if (ws_size >= NEED) {
        unsigned short* Qb  = (unsigned short*)d_ws;
        unsigned short* Kb  = Qb + NEL;
        unsigned short* Vtb = Kb + NEL;
        const int n4 = (int)(NEL / 4);
        cast_bf16_kernel<<<768, 256, 0, stream>>>(q, Qb, n4);
        cast_bf16_kernel<<<768, 256, 0, stream>>>(k, Kb, n4);
        transpose_v_kernel<<<dim3(S / 64, BH), 256, 0, stream>>>(v, Vtb);
        sdpa_main<<<768, 256, 0, stream>>>(Qb, Kb, Vtb, out, attn);
    } else {
        dim3 grid(S / QT, BH);
        sdpa_fallback<<<grid, 256, 0, stream>>>(q, k, v, out, attn);
    }
}

// Round 6
// 155.094 us; speedup vs baseline: 1.8318x; 1.8318x over previous
//
#include <hip/hip_runtime.h>
#include <hip/hip_bf16.h>

namespace {

constexpr int S = 2048;
constexpr int D = 64;
constexpr int BH = 24;        // 2 batches * 12 heads
constexpr int QT = 64;        // q rows per block
constexpr int KT = 64;        // keys per tile
constexpr int NKT = S / KT;   // 32
constexpr int PAD = 72;       // LDS row stride in ushorts (16B-aligned rows; R2 lesson)

typedef __attribute__((ext_vector_type(8))) __bf16 bf16x8;
typedef __attribute__((ext_vector_type(4))) __bf16 bf16x4;
typedef __attribute__((ext_vector_type(4))) float  f32x4;

// f32x4 -> bf16x4 via native v_cvt_pk_bf16_f32 (RNE)
__device__ inline bf16x4 cvt4(f32x4 f) {
    return __builtin_convertvector(f, bf16x4);
}

// ================= kernel 1: row sums of exp(scores/64) -> inv, ws =================
// LDS 27.6KB -> 5 blocks/CU (20 waves): barrier stalls of one block hide under others.
__global__ __launch_bounds__(256, 5)
void rowsum_kernel(const float* __restrict__ q,
                   const float* __restrict__ k,
                   float* __restrict__ invrs) {
    __shared__ unsigned short Ks[2][KT][PAD];
    __shared__ unsigned short QPs[QT][PAD];

    const int tid  = threadIdx.x;
    const int wid  = tid >> 6;
    const int lane = tid & 63;
    const int g    = lane >> 4;
    const int r16  = lane & 15;
    const int bh   = blockIdx.y;
    const int q0   = blockIdx.x * QT;

    const float* qg = q + ((size_t)bh * S + q0) * D;
    const float* kg = k + (size_t)bh * S * D;

    #pragma unroll
    for (int ii = 0; ii < 4; ++ii) {
        int idx = tid + ii * 256;
        int r = idx >> 4, c = (idx & 15) * 4;
        f32x4 f = *reinterpret_cast<const f32x4*>(qg + r * D + c);
        *reinterpret_cast<bf16x4*>(&QPs[r][c]) = cvt4(f);
    }
    __syncthreads();
    const bf16x8 bQ0 = *(const bf16x8*)&QPs[wid * 16 + r16][g * 8];
    const bf16x8 bQ1 = *(const bf16x8*)&QPs[wid * 16 + r16][32 + g * 8];

    float rs0 = 0.f, rs1 = 0.f;   // 2 accumulators: shorter dep chains
    f32x4 pK[4];

    #pragma unroll
    for (int ii = 0; ii < 4; ++ii) {
        int idx = tid + ii * 256;
        int r = idx >> 4, c = (idx & 15) * 4;
        pK[ii] = *reinterpret_cast<const f32x4*>(kg + r * D + c);
    }
    #pragma unroll
    for (int ii = 0; ii < 4; ++ii) {
        int idx = tid + ii * 256;
        int r = idx >> 4, c = (idx & 15) * 4;
        *reinterpret_cast<bf16x4*>(&Ks[0][r][c]) = cvt4(pK[ii]);
    }
    __syncthreads();

    for (int t = 0; t < NKT; ++t) {
        const int cur = t & 1;
        if (t + 1 < NKT) {
            const float* ktg = kg + (size_t)(t + 1) * KT * D;
            #pragma unroll
            for (int ii = 0; ii < 4; ++ii) {
                int idx = tid + ii * 256;
                int r = idx >> 4, c = (idx & 15) * 4;
                pK[ii] = *reinterpret_cast<const f32x4*>(ktg + r * D + c);
            }
        }
        #pragma unroll
        for (int cf = 0; cf < 4; ++cf) {
            bf16x8 aK0 = *(const bf16x8*)&Ks[cur][cf * 16 + r16][g * 8];
            bf16x8 aK1 = *(const bf16x8*)&Ks[cur][cf * 16 + r16][32 + g * 8];
            f32x4 acc = {0.f, 0.f, 0.f, 0.f};
            acc = __builtin_amdgcn_mfma_f32_16x16x32_bf16(aK0, bQ0, acc, 0, 0, 0);
            acc = __builtin_amdgcn_mfma_f32_16x16x32_bf16(aK1, bQ1, acc, 0, 0, 0);
            rs0 += __expf(acc[0] * (1.0f / 64.0f)) + __expf(acc[2] * (1.0f / 64.0f));
            rs1 += __expf(acc[1] * (1.0f / 64.0f)) + __expf(acc[3] * (1.0f / 64.0f));
        }
        if (t + 1 < NKT) {
            const int nxt = (t + 1) & 1;
            #pragma unroll
            for (int ii = 0; ii < 4; ++ii) {
                int idx = tid + ii * 256;
                int r = idx >> 4, c = (idx & 15) * 4;
                *reinterpret_cast<bf16x4*>(&Ks[nxt][r][c]) = cvt4(pK[ii]);
            }
            __syncthreads();
        }
    }
    float rs = rs0 + rs1;
    rs += __shfl_xor(rs, 16, 64);
    rs += __shfl_xor(rs, 32, 64);
    if (lane < 16)
        invrs[(size_t)bh * S + q0 + wid * 16 + lane] = 1.0f / rs;
}

// ============ kernel 2: recompute scores, write attn (nt), accumulate PV ============
// Single-buffered K/V: LDS 27.6KB -> 5 blocks/CU. 2 barriers/tile, but independent
// blocks stagger so the 410MB attn write stream stays continuously busy.
__global__ __launch_bounds__(256, 5)
void attn_pv_kernel(const float* __restrict__ q,
                    const float* __restrict__ k,
                    const float* __restrict__ v,
                    const float* __restrict__ invrs,
                    float* __restrict__ out,
                    float* __restrict__ attn) {
    __shared__ unsigned short Ks[KT][PAD];
    __shared__ unsigned short Vt[D][PAD];    // Vt[d][key]
    __shared__ unsigned short QPs[QT][PAD];  // Q staging, then P (rows wave-private)

    const int tid  = threadIdx.x;
    const int wid  = tid >> 6;
    const int lane = tid & 63;
    const int g    = lane >> 4;
    const int r16  = lane & 15;
    const int bh   = blockIdx.y;
    const int q0   = blockIdx.x * QT;

    const float* qg = q + ((size_t)bh * S + q0) * D;
    const float* kg = k + (size_t)bh * S * D;
    const float* vg = v + (size_t)bh * S * D;
    float* attng = attn + ((size_t)bh * S + q0) * S;
    float* outg  = out  + ((size_t)bh * S + q0) * D;

    #pragma unroll
    for (int ii = 0; ii < 4; ++ii) {
        int idx = tid + ii * 256;
        int r = idx >> 4, c = (idx & 15) * 4;
        f32x4 f = *reinterpret_cast<const f32x4*>(qg + r * D + c);
        *reinterpret_cast<bf16x4*>(&QPs[r][c]) = cvt4(f);
    }
    __syncthreads();
    // Own-wave rows only; later P writes also touch own-wave rows only -> no hazard.
    const bf16x8 bQ0 = *(const bf16x8*)&QPs[wid * 16 + r16][g * 8];
    const bf16x8 bQ1 = *(const bf16x8*)&QPs[wid * 16 + r16][32 + g * 8];

    const float inv = invrs[(size_t)bh * S + q0 + wid * 16 + r16];

    f32x4 oacc[4];
    #pragma unroll
    for (int n = 0; n < 4; ++n) oacc[n] = {0.f, 0.f, 0.f, 0.f};

    f32x4 pK[4], pV[4];
    const int vk0 = (tid & 15) * 4;   // V: 4 rows x float4 -> transposed b64 writes
    const int vc  = (tid >> 4) * 4;

    // prologue: stage tile 0
    #pragma unroll
    for (int ii = 0; ii < 4; ++ii) {
        int idx = tid + ii * 256;
        int r = idx >> 4, c = (idx & 15) * 4;
        pK[ii] = *reinterpret_cast<const f32x4*>(kg + r * D + c);
        pV[ii] = *reinterpret_cast<const f32x4*>(vg + (vk0 + ii) * D + vc);
    }
    #pragma unroll
    for (int ii = 0; ii < 4; ++ii) {
        int idx = tid + ii * 256;
        int r = idx >> 4, c = (idx & 15) * 4;
        *reinterpret_cast<bf16x4*>(&Ks[r][c]) = cvt4(pK[ii]);
    }
    #pragma unroll
    for (int j = 0; j < 4; ++j) {
        f32x4 col = { pV[0][j], pV[1][j], pV[2][j], pV[3][j] };
        *reinterpret_cast<bf16x4*>(&Vt[vc + j][vk0]) = cvt4(col);
    }
    __syncthreads();

    for (int t = 0; t < NKT; ++t) {
        if (t + 1 < NKT) {   // issue next tile's loads; latency hides under compute
            const float* ktg = kg + (size_t)(t + 1) * KT * D;
            const float* vtg = vg + (size_t)(t + 1) * KT * D;
            #pragma unroll
            for (int ii = 0; ii < 4; ++ii) {
                int idx = tid + ii * 256;
                int r = idx >> 4, c = (idx & 15) * 4;
                pK[ii] = *reinterpret_cast<const f32x4*>(ktg + r * D + c);
                pV[ii] = *reinterpret_cast<const f32x4*>(vtg + (vk0 + ii) * D + vc);
            }
        }
        #pragma unroll
        for (int cf = 0; cf < 4; ++cf) {
            bf16x8 aK0 = *(const bf16x8*)&Ks[cf * 16 + r16][g * 8];
            bf16x8 aK1 = *(const bf16x8*)&Ks[cf * 16 + r16][32 + g * 8];
            f32x4 acc = {0.f, 0.f, 0.f, 0.f};
            acc = __builtin_amdgcn_mfma_f32_16x16x32_bf16(aK0, bQ0, acc, 0, 0, 0);
            acc = __builtin_amdgcn_mfma_f32_16x16x32_bf16(aK1, bQ1, acc, 0, 0, 0);
            f32x4 pst;
            #pragma unroll
            for (int e = 0; e < 4; ++e)
                pst[e] = __expf(acc[e] * (1.0f / 64.0f)) * inv;
            __builtin_nontemporal_store(pst, reinterpret_cast<f32x4*>(
                attng + (size_t)(wid * 16 + r16) * S + t * KT + cf * 16 + g * 4));
            *reinterpret_cast<bf16x4*>(&QPs[wid * 16 + r16][cf * 16 + g * 4]) = cvt4(pst);
        }
        bf16x8 aP0 = *(const bf16x8*)&QPs[wid * 16 + r16][g * 8];
        bf16x8 aP1 = *(const bf16x8*)&QPs[wid * 16 + r16][32 + g * 8];
        #pragma unroll
        for (int n = 0; n < 4; ++n) {
            bf16x8 bv0 = *(const bf16x8*)&Vt[n * 16 + r16][g * 8];
            bf16x8 bv1 = *(const bf16x8*)&Vt[n * 16 + r16][32 + g * 8];
            oacc[n] = __builtin_amdgcn_mfma_f32_16x16x32_bf16(aP0, bv0, oacc[n], 0, 0, 0);
            oacc[n] = __builtin_amdgcn_mfma_f32_16x16x32_bf16(aP1, bv1, oacc[n], 0, 0, 0);
        }
        if (t + 1 < NKT) {
            __syncthreads();   // all waves done consuming tile t
            #pragma unroll
            for (int ii = 0; ii < 4; ++ii) {
                int idx = tid + ii * 256;
                int r = idx >> 4, c = (idx & 15) * 4;
                *reinterpret_cast<bf16x4*>(&Ks[r][c]) = cvt4(pK[ii]);
            }
            #pragma unroll
            for (int j = 0; j < 4; ++j) {
                f32x4 col = { pV[0][j], pV[1][j], pV[2][j], pV[3][j] };
                *reinterpret_cast<bf16x4*>(&Vt[vc + j][vk0]) = cvt4(col);
            }
            __syncthreads();   // tile t+1 staged
        }
    }

    #pragma unroll
    for (int n = 0; n < 4; ++n) {
        #pragma unroll
        for (int e = 0; e < 4; ++e) {
            __builtin_nontemporal_store(oacc[n][e],
                outg + (size_t)(wid * 16 + g * 4 + e) * D + n * 16 + r16);
        }
    }
}

// ---------------- fallback (proven R4 monolith) if ws too small ----------------
__global__ __launch_bounds__(256, 3)
void sdpa_fallback(const float* __restrict__ q,
                   const float* __restrict__ k,
                   const float* __restrict__ v,
                   float* __restrict__ out,
                   float* __restrict__ attn) {
    __shared__ unsigned short Ks[2][KT][PAD];
    __shared__ unsigned short Vt[2][D][PAD];
    __shared__ unsigned short QPs[QT][PAD];

    const int tid  = threadIdx.x;
    const int wid  = tid >> 6;
    const int lane = tid & 63;
    const int g    = lane >> 4;
    const int r16  = lane & 15;
    const int bh   = blockIdx.y;
    const int q0   = blockIdx.x * QT;

    const float* qg = q + ((size_t)bh * S + q0) * D;
    const float* kg = k + (size_t)bh * S * D;
    const float* vg = v + (size_t)bh * S * D;
    float* attng = attn + ((size_t)bh * S + q0) * S;
    float* outg  = out  + ((size_t)bh * S + q0) * D;

    #pragma unroll
    for (int ii = 0; ii < 4; ++ii) {
        int idx = tid + ii * 256;
        int r = idx >> 4, c = (idx & 15) * 4;
        f32x4 f = *reinterpret_cast<const f32x4*>(qg + r * D + c);
        *reinterpret_cast<bf16x4*>(&QPs[r][c]) = cvt4(f);
    }
    __syncthreads();
    const bf16x8 bQ0 = *(const bf16x8*)&QPs[wid * 16 + r16][g * 8];
    const bf16x8 bQ1 = *(const bf16x8*)&QPs[wid * 16 + r16][32 + g * 8];

    float rs = 0.0f;
    f32x4 pK[4];

    #pragma unroll
    for (int ii = 0; ii < 4; ++ii) {
        int idx = tid + ii * 256;
        int r = idx >> 4, c = (idx & 15) * 4;
        pK[ii] = *reinterpret_cast<const f32x4*>(kg + r * D + c);
    }
    #pragma unroll
    for (int ii = 0; ii < 4; ++ii) {
        int idx = tid + ii * 256;
        int r = idx >> 4, c = (idx & 15) * 4;
        *reinterpret_cast<bf16x4*>(&Ks[0][r][c]) = cvt4(pK[ii]);
    }
    __syncthreads();

    for (int t = 0; t < NKT; ++t) {
        const int cur = t & 1;
        if (t + 1 < NKT) {
            const float* ktg = kg + (size_t)(t + 1) * KT * D;
            #pragma unroll
            for (int ii = 0; ii < 4; ++ii) {
                int idx = tid + ii * 256;
                int r = idx >> 4, c = (idx & 15) * 4;
                pK[ii] = *reinterpret_cast<const f32x4*>(ktg + r * D + c);
            }
        }
        #pragma unroll
        for (int cf = 0; cf < 4; ++cf) {
            bf16x8 aK0 = *(const bf16x8*)&Ks[cur][cf * 16 + r16][g * 8];
            bf16x8 aK1 = *(const bf16x8*)&Ks[cur][cf * 16 + r16][32 + g * 8];
            f32x4 acc = {0.f, 0.f, 0.f, 0.f};
            acc = __builtin_amdgcn_mfma_f32_16x16x32_bf16(aK0, bQ0, acc, 0, 0, 0);
            acc = __builtin_amdgcn_mfma_f32_16x16x32_bf16(aK1, bQ1, acc, 0, 0, 0);
            #pragma unroll
            for (int e = 0; e < 4; ++e)
                rs += __expf(acc[e] * (1.0f / 64.0f));
        }
        if (t + 1 < NKT) {
            const int nxt = (t + 1) & 1;
            #pragma unroll
            for (int ii = 0; ii < 4; ++ii) {
                int idx = tid + ii * 256;
                int r = idx >> 4, c = (idx & 15) * 4;
                *reinterpret_cast<bf16x4*>(&Ks[nxt][r][c]) = cvt4(pK[ii]);
            }
            __syncthreads();
        }
    }
    rs += __shfl_xor(rs, 16, 64);
    rs += __shfl_xor(rs, 32, 64);
    const float inv = 1.0f / rs;

    f32x4 oacc[4];
    #pragma unroll
    for (int n = 0; n < 4; ++n) oacc[n] = {0.f, 0.f, 0.f, 0.f};

    f32x4 pV[4];
    const int vk0 = (tid & 15) * 4;
    const int vc  = (tid >> 4) * 4;

    #pragma unroll
    for (int ii = 0; ii < 4; ++ii) {
        int idx = tid + ii * 256;
        int r = idx >> 4, c = (idx & 15) * 4;
        pK[ii] = *reinterpret_cast<const f32x4*>(kg + r * D + c);
        pV[ii] = *reinterpret_cast<const f32x4*>(vg + (vk0 + ii) * D + vc);
    }
    #pragma unroll
    for (int ii = 0; ii < 4; ++ii) {
        int idx = tid + ii * 256;
        int r = idx >> 4, c = (idx & 15) * 4;
        *reinterpret_cast<bf16x4*>(&Ks[0][r][c]) = cvt4(pK[ii]);
    }
    #pragma unroll
    for (int j = 0; j < 4; ++j) {
        f32x4 col = { pV[0][j], pV[1][j], pV[2][j], pV[3][j] };
        *reinterpret_cast<bf16x4*>(&Vt[0][vc + j][vk0]) = cvt4(col);
    }
    __syncthreads();

    for (int t = 0; t < NKT; ++t) {
        const int cur = t & 1;
        if (t + 1 < NKT) {
            const float* ktg = kg + (size_t)(t + 1) * KT * D;
            const float* vtg = vg + (size_t)(t + 1) * KT * D;
            #pragma unroll
            for (int ii = 0; ii < 4; ++ii) {
                int idx = tid + ii * 256;
                int r = idx >> 4, c = (idx & 15) * 4;
                pK[ii] = *reinterpret_cast<const f32x4*>(ktg + r * D + c);
                pV[ii] = *reinterpret_cast<const f32x4*>(vtg + (vk0 + ii) * D + vc);
            }
        }
        #pragma unroll
        for (int cf = 0; cf < 4; ++cf) {
            bf16x8 aK0 = *(const bf16x8*)&Ks[cur][cf * 16 + r16][g * 8];
            bf16x8 aK1 = *(const bf16x8*)&Ks[cur][cf * 16 + r16][32 + g * 8];
            f32x4 acc = {0.f, 0.f, 0.f, 0.f};
            acc = __builtin_amdgcn_mfma_f32_16x16x32_bf16(aK0, bQ0, acc, 0, 0, 0);
            acc = __builtin_amdgcn_mfma_f32_16x16x32_bf16(aK1, bQ1, acc, 0, 0, 0);
            f32x4 pst;
            #pragma unroll
            for (int e = 0; e < 4; ++e)
                pst[e] = __expf(acc[e] * (1.0f / 64.0f)) * inv;
            __builtin_nontemporal_store(pst, reinterpret_cast<f32x4*>(
                attng + (size_t)(wid * 16 + r16) * S + t * KT + cf * 16 + g * 4));
            *reinterpret_cast<bf16x4*>(&QPs[wid * 16 + r16][cf * 16 + g * 4]) = cvt4(pst);
        }
        bf16x8 aP0 = *(const bf16x8*)&QPs[wid * 16 + r16][g * 8];
        bf16x8 aP1 = *(const bf16x8*)&QPs[wid * 16 + r16][32 + g * 8];
        #pragma unroll
        for (int n = 0; n < 4; ++n) {
            bf16x8 bv0 = *(const bf16x8*)&Vt[cur][n * 16 + r16][g * 8];
            bf16x8 bv1 = *(const bf16x8*)&Vt[cur][n * 16 + r16][32 + g * 8];
            oacc[n] = __builtin_amdgcn_mfma_f32_16x16x32_bf16(aP0, bv0, oacc[n], 0, 0, 0);
            oacc[n] = __builtin_amdgcn_mfma_f32_16x16x32_bf16(aP1, bv1, oacc[n], 0, 0, 0);
        }
        if (t + 1 < NKT) {
            const int nxt = (t + 1) & 1;
            #pragma unroll
            for (int ii = 0; ii < 4; ++ii) {
                int idx = tid + ii * 256;
                int r = idx >> 4, c = (idx & 15) * 4;
                *reinterpret_cast<bf16x4*>(&Ks[nxt][r][c]) = cvt4(pK[ii]);
            }
            #pragma unroll
            for (int j = 0; j < 4; ++j) {
                f32x4 col = { pV[0][j], pV[1][j], pV[2][j], pV[3][j] };
                *reinterpret_cast<bf16x4*>(&Vt[nxt][vc + j][vk0]) = cvt4(col);
            }
            __syncthreads();
        }
    }

    #pragma unroll
    for (int n = 0; n < 4; ++n) {
        #pragma unroll
        for (int e = 0; e < 4; ++e) {
            __builtin_nontemporal_store(oacc[n][e],
                outg + (size_t)(wid * 16 + g * 4 + e) * D + n * 16 + r16);
        }
    }
}

} // namespace

extern "C" void kernel_launch(void* const* d_in, const int* in_sizes, int n_in,
                              void* d_out, int out_size, void* d_ws, size_t ws_size,
                              hipStream_t stream) {
    const float* q = (const float*)d_in[0];
    const float* k = (const float*)d_in[1];
    const float* v = (const float*)d_in[2];
    float* out  = (float*)d_out;
    float* attn = out + (size_t)BH * S * D;   // outputs concatenated: (out, attn)

    constexpr size_t RS_BYTES = (size_t)BH * S * sizeof(float);   // 196 KB

    if (ws_size >= RS_BYTES) {
        float* invrs = (float*)d_ws;
        dim3 grid(S / QT, BH);
        rowsum_kernel<<<grid, 256, 0, stream>>>(q, k, invrs);
        attn_pv_kernel<<<grid, 256, 0, stream>>>(q, k, v, invrs, out, attn);
    } else {
        dim3 grid(S / QT, BH);
        sdpa_fallback<<<grid, 256, 0, stream>>>(q, k, v, out, attn);
    }
}